// Round 5
// baseline (1502.875 us; speedup 1.0000x reference)
//
#include <hip/hip_runtime.h>
#include <stdint.h>

#define SEQ 2048
#define DM 4096
#define NHEADS 16
#define DHEAD 256
#define DFF 16384

typedef __attribute__((ext_vector_type(8))) short short8;
typedef __attribute__((ext_vector_type(4))) float f32x4;
typedef __attribute__((ext_vector_type(4))) float float4v;
typedef __attribute__((ext_vector_type(4))) unsigned short ushort4v;
typedef __attribute__((ext_vector_type(8))) unsigned short ushort8v;

__device__ __forceinline__ unsigned short f2b(float f) {
    uint32_t u = __builtin_bit_cast(uint32_t, f);
    u = (u + 0x7FFFu + ((u >> 16) & 1u)) >> 16;
    return (unsigned short)u;
}

__device__ __forceinline__ void gload_lds16(const void* g, void* l) {
    __builtin_amdgcn_global_load_lds((const __attribute__((address_space(1))) void*)g,
                                     (__attribute__((address_space(3))) void*)l, 16, 0, 0);
}

// ---------------- transpose + (optional f32->bf16) convert ----------------
template <typename T>
__global__ __launch_bounds__(256) void transpose_cvt(const T* __restrict__ src,
                                                     unsigned short* __restrict__ dst,
                                                     int ldS, int ldD, int R, int C) {
    __shared__ unsigned short tl[64 * 66];
    int r0 = blockIdx.y << 6, c0 = blockIdx.x << 6;
    int tid = threadIdx.x;
#pragma unroll
    for (int it = 0; it < 4; ++it) {
        int e = (tid + it * 256) * 4;
        int rr = e >> 6, cc = e & 63;
        const T* sp = src + (size_t)(r0 + rr) * ldS + c0 + cc;
        if constexpr (sizeof(T) == 4) {
            float4v v = *(const float4v*)sp;
#pragma unroll
            for (int j = 0; j < 4; ++j) tl[rr * 66 + cc + j] = f2b(v[j]);
        } else {
            ushort4v v = *(const ushort4v*)sp;
#pragma unroll
            for (int j = 0; j < 4; ++j) tl[rr * 66 + cc + j] = v[j];
        }
    }
    __syncthreads();
#pragma unroll
    for (int it = 0; it < 2; ++it) {
        int e = tid + it * 256;
        int oc = e >> 3;
        int k8 = (e & 7) * 8;
        ushort8v w;
#pragma unroll
        for (int j = 0; j < 8; ++j) w[j] = tl[(k8 + j) * 66 + oc];
        *(ushort8v*)(dst + (size_t)(c0 + oc) * ldD + r0 + k8) = w;
    }
}

// ---------------- LayerNorm ----------------
__global__ __launch_bounds__(256) void ln_kernel(const float* __restrict__ x,
                                                 const float* __restrict__ sc,
                                                 const float* __restrict__ of,
                                                 unsigned short* __restrict__ h) {
    int row = blockIdx.x;
    int tid = threadIdx.x, lane = tid & 63, wave = tid >> 6;
    const float4v* xr = (const float4v*)(x + (size_t)row * DM);
    float4v v[4];
    float s = 0.f, s2 = 0.f;
#pragma unroll
    for (int i = 0; i < 4; ++i) {
        v[i] = xr[tid + i * 256];
#pragma unroll
        for (int j = 0; j < 4; ++j) { s += v[i][j]; s2 += v[i][j] * v[i][j]; }
    }
#pragma unroll
    for (int o = 1; o < 64; o <<= 1) { s += __shfl_xor(s, o); s2 += __shfl_xor(s2, o); }
    __shared__ float rs[4], rs2[4];
    if (lane == 0) { rs[wave] = s; rs2[wave] = s2; }
    __syncthreads();
    s = rs[0] + rs[1] + rs[2] + rs[3];
    s2 = rs2[0] + rs2[1] + rs2[2] + rs2[3];
    float mean = s * (1.0f / DM);
    float var = s2 * (1.0f / DM) - mean * mean;
    float inv = rsqrtf(var + 1e-5f);
#pragma unroll
    for (int i = 0; i < 4; ++i) {
        int c = (tid + i * 256) * 4;
        ushort4v o4;
#pragma unroll
        for (int j = 0; j < 4; ++j)
            o4[j] = f2b((v[i][j] - mean) * inv * sc[c + j] + of[c + j]);
        *(ushort4v*)(h + (size_t)row * DM + c) = o4;
    }
}

// ---------------- GEMM: C[M,N] = A[M,K](bf16) * BT[N,K]^T (bf16) ----------------
// 128x128 tile, BK=64, 4 waves, 64KB LDS -> 2 blocks/CU. Double-buffered, counted
// vmcnt(8), XOR swizzle (row&7)<<4 (SQ_LDS_BANK_CONFLICT=0 verified r2/r4).
// Block mapping (r5): column-slab-per-XCD, by-fastest. XCD k owns bx slab
// [k*nbx/8,(k+1)*nbx/8); within slab iterate by innermost -> B slab gets x16 L2
// reuse inside one XCD; A (small, read by all XCDs) stays L3-resident.
#define MF(a, b, c) __builtin_amdgcn_mfma_f32_16x16x32_bf16(a, b, c, 0, 0, 0)

template <int EPI>
__global__ __launch_bounds__(256, 2) void gemm128(const unsigned short* __restrict__ A,
                                                  const unsigned short* __restrict__ BT,
                                                  void* __restrict__ Cout,
                                                  int M, int N, int K, int ldc,
                                                  const float* __restrict__ bias,
                                                  const float* __restrict__ addm) {
    __shared__ unsigned short aL[2][128 * 64];  // 32 KB
    __shared__ unsigned short bL[2][128 * 64];  // 32 KB

    const int nby = M >> 7;
    const int nbx = N >> 7;
    // column-slab-per-XCD mapping (requires nbx%8==0 && nwg%8==0 - true for all grids)
    const int slabw = nbx >> 3;
    int b = blockIdx.x;
    int xcd = b & 7;
    int j = b >> 3;
    const int bx = xcd * slabw + j / nby;
    const int by = j % nby;
    const int bm0 = by << 7, bn0 = bx << 7;

    const int tid = threadIdx.x, lane = tid & 63, wave = tid >> 6;
    const int wm = wave >> 1, wn = wave & 1;
    const int l15 = lane & 15, kl = lane >> 4;

    // staging: thread -> 16B granule; pre-swizzled global source so linear LDS dest
    // + swizzled reads agree.
    const int rh = tid >> 3;
    const int cb_s = (tid & 7) << 4;
    const int kx = (cb_s ^ ((rh & 7) << 4)) >> 1;

    const unsigned short* Abase = A + (size_t)(bm0 + rh) * K + kx;
    const unsigned short* Bbase = BT + (size_t)(bn0 + rh) * K + kx;

    auto stage = [&](int v) {
        const unsigned short* ga = Abase + (size_t)v * 64;
        const unsigned short* gb = Bbase + (size_t)v * 64;
        char* la = (char*)aL[v & 1] + tid * 16;
        char* lb = (char*)bL[v & 1] + tid * 16;
#pragma unroll
        for (int h = 0; h < 4; ++h) gload_lds16(ga + (size_t)(h * 32) * K, la + h * 4096);
#pragma unroll
        for (int h = 0; h < 4; ++h) gload_lds16(gb + (size_t)(h * 32) * K, lb + h * 4096);
    };

    const int arow = wm * 64 + l15;
    const int brow = wn * 64 + l15;
    const int sa = (arow & 7) << 4;
    const int sb = (brow & 7) << 4;
    const int ca0 = ((kl * 16) ^ sa) >> 1;
    const int ca1 = ((64 + kl * 16) ^ sa) >> 1;
    const int cb0 = ((kl * 16) ^ sb) >> 1;
    const int cb1 = ((64 + kl * 16) ^ sb) >> 1;

    f32x4 acc[4][4];
#pragma unroll
    for (int i = 0; i < 4; ++i)
#pragma unroll
        for (int j2 = 0; j2 < 4; ++j2) acc[i][j2] = (f32x4){0.f, 0.f, 0.f, 0.f};

    const int NT = K >> 6;
    stage(0);
    for (int u = 0; u < NT; ++u) {
        if (u + 1 < NT) {
            stage(u + 1);
            asm volatile("s_waitcnt vmcnt(8)" ::: "memory");  // tile u landed; u+1 in flight
        } else {
            asm volatile("s_waitcnt vmcnt(0)" ::: "memory");
        }
        __builtin_amdgcn_s_barrier();

        const unsigned short* aB = aL[u & 1];
        const unsigned short* bB = bL[u & 1];
        short8 af[4][2], bf[4][2];
#pragma unroll
        for (int i = 0; i < 4; ++i) {
            af[i][0] = *(const short8*)(aB + (arow + i * 16) * 64 + ca0);
            af[i][1] = *(const short8*)(aB + (arow + i * 16) * 64 + ca1);
        }
#pragma unroll
        for (int j2 = 0; j2 < 4; ++j2) {
            bf[j2][0] = *(const short8*)(bB + (brow + j2 * 16) * 64 + cb0);
            bf[j2][1] = *(const short8*)(bB + (brow + j2 * 16) * 64 + cb1);
        }
#pragma unroll
        for (int kk = 0; kk < 2; ++kk)
#pragma unroll
            for (int i = 0; i < 4; ++i)
#pragma unroll
                for (int j2 = 0; j2 < 4; ++j2)
                    acc[i][j2] = MF(af[i][kk], bf[j2][kk], acc[i][j2]);

        // all my ds_reads done before any wave stages tile u+2 into buf[u&1]
        asm volatile("s_waitcnt lgkmcnt(0)" ::: "memory");
        __builtin_amdgcn_s_barrier();
    }

    // epilogue
    const int r0 = bm0 + wm * 64 + kl * 4;
    const int c0g = bn0 + wn * 64 + l15;
#pragma unroll
    for (int i = 0; i < 4; ++i) {
#pragma unroll
        for (int j2 = 0; j2 < 4; ++j2) {
            int col = c0g + j2 * 16;
#pragma unroll
            for (int r = 0; r < 4; ++r) {
                int row = r0 + i * 16 + r;
                float v = acc[i][j2][r];
                if constexpr (EPI == 0) {
                    ((unsigned short*)Cout)[(size_t)row * ldc + col] = f2b(v);
                } else if constexpr (EPI == 1) {
                    ((float*)Cout)[(size_t)row * ldc + col] = v;
                } else if constexpr (EPI == 2) {
                    v += bias[col];
                    float t = tanhf(0.7978845608f * (v + 0.044715f * v * v * v));
                    ((unsigned short*)Cout)[(size_t)row * ldc + col] = f2b(0.5f * v * (1.0f + t));
                } else {
                    v += bias[col] + addm[(size_t)row * ldc + col];
                    ((float*)Cout)[(size_t)row * ldc + col] = v;
                }
            }
        }
    }
}

// ---------------- flash attention ----------------
__global__ __launch_bounds__(256, 2) void attn_kernel(const unsigned short* __restrict__ qkv,
                                                      const unsigned short* __restrict__ vT,
                                                      const float* __restrict__ bias,
                                                      unsigned short* __restrict__ attn_vec) {
    __shared__ unsigned short kL[64 * 264];
    __shared__ unsigned short vL[256 * 72];
    __shared__ unsigned short pL[4][16 * 72];

    int qb = blockIdx.x, head = blockIdx.y;
    int tid = threadIdx.x, lane = tid & 63, wave = tid >> 6;
    int q16 = lane & 15, q4 = lane >> 4;

    short8 qf[8];
    {
        const unsigned short* qp =
            qkv + (size_t)(qb * 64 + wave * 16 + q16) * (3 * DM) + head * DHEAD + (q4 << 3);
#pragma unroll
        for (int kk = 0; kk < 8; ++kk) qf[kk] = *(const short8*)(qp + kk * 32);
    }

    f32x4 o[16];
#pragma unroll
    for (int d = 0; d < 16; ++d) o[d] = (f32x4){0.f, 0.f, 0.f, 0.f};
    float m_run[4] = {-INFINITY, -INFINITY, -INFINITY, -INFINITY};
    float l_run[4] = {0.f, 0.f, 0.f, 0.f};
    int qrow0 = qb * 64 + wave * 16 + q4 * 4;

    for (int t = 0; t <= qb; ++t) {
        int kv0 = t * 64;
#pragma unroll
        for (int rr = 0; rr < 8; ++rr) {
            int i = tid + rr * 256;
            int row = i >> 5, c8 = (i & 31) << 3;
            *(ushort8v*)(kL + row * 264 + c8) =
                *(const ushort8v*)(qkv + (size_t)(kv0 + row) * (3 * DM) + DM + head * DHEAD + c8);
        }
#pragma unroll
        for (int rr = 0; rr < 8; ++rr) {
            int i = tid + rr * 256;
            int d = i >> 3, c8 = (i & 7) << 3;
            *(ushort8v*)(vL + d * 72 + c8) =
                *(const ushort8v*)(vT + (size_t)(head * DHEAD + d) * SEQ + kv0 + c8);
        }
        __syncthreads();

        f32x4 s[4];
#pragma unroll
        for (int c = 0; c < 4; ++c) s[c] = (f32x4){0.f, 0.f, 0.f, 0.f};
#pragma unroll
        for (int kk = 0; kk < 8; ++kk) {
#pragma unroll
            for (int c = 0; c < 4; ++c) {
                short8 kf = *(const short8*)(kL + (c * 16 + q16) * 264 + kk * 32 + (q4 << 3));
                s[c] = __builtin_amdgcn_mfma_f32_16x16x32_bf16(qf[kk], kf, s[c], 0, 0, 0);
            }
        }

        bool diag = (t == qb);
#pragma unroll
        for (int r = 0; r < 4; ++r) {
            int qr = qrow0 + r;
            float sv[4];
#pragma unroll
            for (int c = 0; c < 4; ++c) {
                float vv = s[c][r] * 0.0625f + bias[(size_t)qr * SEQ + kv0 + c * 16 + q16];
                if (diag && (kv0 + c * 16 + q16) > qr) vv = -1e30f;
                sv[c] = vv;
            }
            float m = fmaxf(fmaxf(sv[0], sv[1]), fmaxf(sv[2], sv[3]));
#pragma unroll
            for (int off = 1; off < 16; off <<= 1) m = fmaxf(m, __shfl_xor(m, off));
            float mn = fmaxf(m_run[r], m);
            float alpha = __expf(m_run[r] - mn);
            float psum = 0.f;
#pragma unroll
            for (int c = 0; c < 4; ++c) {
                float p = __expf(sv[c] - mn);
                psum += p;
                pL[wave][(q4 * 4 + r) * 72 + c * 16 + q16] = f2b(p);
            }
#pragma unroll
            for (int off = 1; off < 16; off <<= 1) psum += __shfl_xor(psum, off);
            l_run[r] = l_run[r] * alpha + psum;
            m_run[r] = mn;
#pragma unroll
            for (int d = 0; d < 16; ++d) o[d][r] *= alpha;
        }

#pragma unroll
        for (int ks = 0; ks < 2; ++ks) {
            short8 pa = *(const short8*)(pL[wave] + q16 * 72 + ks * 32 + (q4 << 3));
#pragma unroll
            for (int d = 0; d < 16; ++d) {
                short8 vb = *(const short8*)(vL + (d * 16 + q16) * 72 + ks * 32 + (q4 << 3));
                o[d] = __builtin_amdgcn_mfma_f32_16x16x32_bf16(pa, vb, o[d], 0, 0, 0);
            }
        }
        __syncthreads();
    }

#pragma unroll
    for (int r = 0; r < 4; ++r) {
        float inv = 1.0f / l_run[r];
#pragma unroll
        for (int d = 0; d < 16; ++d)
            attn_vec[(size_t)(qrow0 + r) * DM + head * DHEAD + d * 16 + q16] = f2b(o[d][r] * inv);
    }
}

// ---------------- launch ----------------
extern "C" void kernel_launch(void* const* d_in, const int* in_sizes, int n_in,
                              void* d_out, int out_size, void* d_ws, size_t ws_size,
                              hipStream_t stream) {
    const float* x = (const float*)d_in[0];
    const float* attn_bias = (const float*)d_in[1];
    const float* ln_scale = (const float*)d_in[2];
    const float* ln_offset = (const float*)d_in[3];
    const float* wq = (const float*)d_in[4];
    const float* wk = (const float*)d_in[5];
    const float* wv = (const float*)d_in[6];
    const float* wo = (const float*)d_in[7];
    const float* w_ffn = (const float*)d_in[8];
    const float* b_ffn = (const float*)d_in[9];
    const float* w_ffn_o = (const float*)d_in[10];
    const float* b_ffn_o = (const float*)d_in[11];
    float* out = (float*)d_out;

    char* p = (char*)d_ws;
    unsigned short* WT_qkv = (unsigned short*)p; p += (size_t)3 * DM * DM * 2;
    unsigned short* WT_o = (unsigned short*)p;   p += (size_t)DM * DM * 2;
    unsigned short* WT_f1 = (unsigned short*)p;  p += (size_t)DFF * DM * 2;
    unsigned short* WT_f2 = (unsigned short*)p;  p += (size_t)DM * DFF * 2;
    unsigned short* hB = (unsigned short*)p;     p += (size_t)SEQ * DM * 2;
    unsigned short* qkvB = (unsigned short*)p;   p += (size_t)SEQ * 3 * DM * 2;
    unsigned short* vTB = (unsigned short*)p;    p += (size_t)DM * SEQ * 2;
    unsigned short* avB = (unsigned short*)p;    p += (size_t)SEQ * DM * 2;
    float* attn_out = (float*)p;                 p += (size_t)SEQ * DM * 4;
    unsigned short* ffB = (unsigned short*)p;    p += (size_t)SEQ * DFF * 2;

    transpose_cvt<float><<<dim3(DM / 64, DM / 64), 256, 0, stream>>>(wq, WT_qkv, DM, DM, DM, DM);
    transpose_cvt<float><<<dim3(DM / 64, DM / 64), 256, 0, stream>>>(wk, WT_qkv + (size_t)DM * DM, DM, DM, DM, DM);
    transpose_cvt<float><<<dim3(DM / 64, DM / 64), 256, 0, stream>>>(wv, WT_qkv + (size_t)2 * DM * DM, DM, DM, DM, DM);
    transpose_cvt<float><<<dim3(DM / 64, DM / 64), 256, 0, stream>>>(wo, WT_o, DM, DM, DM, DM);
    transpose_cvt<float><<<dim3(DFF / 64, DM / 64), 256, 0, stream>>>(w_ffn, WT_f1, DFF, DM, DM, DFF);
    transpose_cvt<float><<<dim3(DM / 64, DFF / 64), 256, 0, stream>>>(w_ffn_o, WT_f2, DM, DFF, DFF, DM);

    ln_kernel<<<SEQ, 256, 0, stream>>>(x, ln_scale, ln_offset, hB);

    // QKV: 16x96 = 1536 blocks
    gemm128<0><<<(SEQ / 128) * (3 * DM / 128), 256, 0, stream>>>(hB, WT_qkv, qkvB, SEQ, 3 * DM, DM, 3 * DM, nullptr, nullptr);
    transpose_cvt<unsigned short><<<dim3(DM / 64, SEQ / 64), 256, 0, stream>>>(qkvB + 2 * DM, vTB, 3 * DM, SEQ, SEQ, DM);

    attn_kernel<<<dim3(SEQ / 64, NHEADS), 256, 0, stream>>>(qkvB, vTB, attn_bias, avB);

    // WO: 16x32 = 512 blocks
    gemm128<1><<<(SEQ / 128) * (DM / 128), 256, 0, stream>>>(avB, WT_o, attn_out, SEQ, DM, DM, DM, nullptr, nullptr);
    // FFN1: 16x128 = 2048 blocks
    gemm128<2><<<(SEQ / 128) * (DFF / 128), 256, 0, stream>>>(hB, WT_f1, ffB, SEQ, DFF, DM, DFF, b_ffn, nullptr);
    // FFN2: 16x32 = 512 blocks
    gemm128<3><<<(SEQ / 128) * (DM / 128), 256, 0, stream>>>(ffB, WT_f2, out, SEQ, DM, DFF, DM, b_ffn_o, attn_out);
}

// Round 6
// 1478.036 us; speedup vs baseline: 1.0168x; 1.0168x over previous
//
#include <hip/hip_runtime.h>
#include <stdint.h>

#define SEQ 2048
#define DM 4096
#define NHEADS 16
#define DHEAD 256
#define DFF 16384

typedef __attribute__((ext_vector_type(8))) short short8;
typedef __attribute__((ext_vector_type(4))) float f32x4;
typedef __attribute__((ext_vector_type(4))) float float4v;
typedef __attribute__((ext_vector_type(4))) unsigned short ushort4v;
typedef __attribute__((ext_vector_type(8))) unsigned short ushort8v;

__device__ __forceinline__ unsigned short f2b(float f) {
    uint32_t u = __builtin_bit_cast(uint32_t, f);
    u = (u + 0x7FFFu + ((u >> 16) & 1u)) >> 16;
    return (unsigned short)u;
}

__device__ __forceinline__ void gload_lds16(const void* g, void* l) {
    __builtin_amdgcn_global_load_lds((const __attribute__((address_space(1))) void*)g,
                                     (__attribute__((address_space(3))) void*)l, 16, 0, 0);
}

// ---------------- transpose + (optional f32->bf16) convert ----------------
template <typename T>
__global__ __launch_bounds__(256) void transpose_cvt(const T* __restrict__ src,
                                                     unsigned short* __restrict__ dst,
                                                     int ldS, int ldD, int R, int C) {
    __shared__ unsigned short tl[64 * 66];
    int r0 = blockIdx.y << 6, c0 = blockIdx.x << 6;
    int tid = threadIdx.x;
#pragma unroll
    for (int it = 0; it < 4; ++it) {
        int e = (tid + it * 256) * 4;
        int rr = e >> 6, cc = e & 63;
        const T* sp = src + (size_t)(r0 + rr) * ldS + c0 + cc;
        if constexpr (sizeof(T) == 4) {
            float4v v = *(const float4v*)sp;
#pragma unroll
            for (int j = 0; j < 4; ++j) tl[rr * 66 + cc + j] = f2b(v[j]);
        } else {
            ushort4v v = *(const ushort4v*)sp;
#pragma unroll
            for (int j = 0; j < 4; ++j) tl[rr * 66 + cc + j] = v[j];
        }
    }
    __syncthreads();
#pragma unroll
    for (int it = 0; it < 2; ++it) {
        int e = tid + it * 256;
        int oc = e >> 3;
        int k8 = (e & 7) * 8;
        ushort8v w;
#pragma unroll
        for (int j = 0; j < 8; ++j) w[j] = tl[(k8 + j) * 66 + oc];
        *(ushort8v*)(dst + (size_t)(c0 + oc) * ldD + r0 + k8) = w;
    }
}

// ---------------- LayerNorm ----------------
__global__ __launch_bounds__(256) void ln_kernel(const float* __restrict__ x,
                                                 const float* __restrict__ sc,
                                                 const float* __restrict__ of,
                                                 unsigned short* __restrict__ h) {
    int row = blockIdx.x;
    int tid = threadIdx.x, lane = tid & 63, wave = tid >> 6;
    const float4v* xr = (const float4v*)(x + (size_t)row * DM);
    float4v v[4];
    float s = 0.f, s2 = 0.f;
#pragma unroll
    for (int i = 0; i < 4; ++i) {
        v[i] = xr[tid + i * 256];
#pragma unroll
        for (int j = 0; j < 4; ++j) { s += v[i][j]; s2 += v[i][j] * v[i][j]; }
    }
#pragma unroll
    for (int o = 1; o < 64; o <<= 1) { s += __shfl_xor(s, o); s2 += __shfl_xor(s2, o); }
    __shared__ float rs[4], rs2[4];
    if (lane == 0) { rs[wave] = s; rs2[wave] = s2; }
    __syncthreads();
    s = rs[0] + rs[1] + rs[2] + rs[3];
    s2 = rs2[0] + rs2[1] + rs2[2] + rs2[3];
    float mean = s * (1.0f / DM);
    float var = s2 * (1.0f / DM) - mean * mean;
    float inv = rsqrtf(var + 1e-5f);
#pragma unroll
    for (int i = 0; i < 4; ++i) {
        int c = (tid + i * 256) * 4;
        ushort4v o4;
#pragma unroll
        for (int j = 0; j < 4; ++j)
            o4[j] = f2b((v[i][j] - mean) * inv * sc[c + j] + of[c + j]);
        *(ushort4v*)(h + (size_t)row * DM + c) = o4;
    }
}

// ---------------- phase-pipelined GEMM: C[M,N] = A[M,K](bf16) * BT[N,K]^T ----------------
// BM=256, BN=128, BK=64, 512 thr (8 waves 4Mx2N, per-wave 64x64), LDS 96KB (1 blk/CU).
// Iteration = 2 K-tiles = 4 phases. Phase = {ds_read frags; issue stage; fence; s_barrier;
// setprio(1); 16 MFMA; setprio(0); [counted vmcnt]; lgkm0; s_barrier}. No sched_barrier
// (r3/m141 lesson). vmcnt(2) at ph2/ph4 only - loads stay in flight across barriers.
// Staging deadlines: A(u+1)@ph1 (buf1 free since prev ph4), B(u+2)@ph2 (bL0 read done ph1),
// A(u+2)h0@ph3 (aL0 done ph2), A(u+2)h1+B(u+3)@ph4 (bL1 done ph3). XOR swizzle (row&7)<<4
// via pre-swizzled global source (conflict-free, verified r2-r5). Column-slab XCD map (r5).
#define MF(a, b, c) __builtin_amdgcn_mfma_f32_16x16x32_bf16(a, b, c, 0, 0, 0)
#define FENCE() asm volatile("" ::: "memory")
#define LGKM0() asm volatile("s_waitcnt lgkmcnt(0)" ::: "memory")

#define RD_B(BT_)                                                                   \
    _Pragma("unroll") for (int j2 = 0; j2 < 4; ++j2) {                              \
        bf[j2][0] = *(const short8*)((BT_) + (brow + j2 * 16) * 64 + ca0);          \
        bf[j2][1] = *(const short8*)((BT_) + (brow + j2 * 16) * 64 + ca1);          \
    }
#define RD_A(AT_, MB)                                                               \
    _Pragma("unroll") for (int i2 = 0; i2 < 2; ++i2) {                              \
        af[i2][0] = *(const short8*)((AT_) + (arow + ((MB) + i2) * 16) * 64 + ca0); \
        af[i2][1] = *(const short8*)((AT_) + (arow + ((MB) + i2) * 16) * 64 + ca1); \
    }
#define MM16(MB)                                                                    \
    __builtin_amdgcn_s_setprio(1);                                                  \
    _Pragma("unroll") for (int kk = 0; kk < 2; ++kk)                                \
        _Pragma("unroll") for (int i2 = 0; i2 < 2; ++i2)                            \
            _Pragma("unroll") for (int j2 = 0; j2 < 4; ++j2)                        \
                acc[(MB) + i2][j2] = MF(af[i2][kk], bf[j2][kk], acc[(MB) + i2][j2]);\
    __builtin_amdgcn_s_setprio(0)

template <int EPI>
__global__ __launch_bounds__(512, 1) void gemm8p(const unsigned short* __restrict__ A,
                                                 const unsigned short* __restrict__ BT,
                                                 void* __restrict__ Cout,
                                                 int M, int N, int K, int ldc,
                                                 const float* __restrict__ bias,
                                                 const float* __restrict__ addm) {
    __shared__ unsigned short aL[2][256 * 64];  // 64 KB
    __shared__ unsigned short bL[2][128 * 64];  // 32 KB

    const int nby = M >> 8;
    const int nbx = N >> 7;
    const int slabw = nbx >> 3;
    int b = blockIdx.x;
    const int xcd = b & 7;
    const int jj = b >> 3;
    const int bx = xcd * slabw + jj / nby;
    const int by = jj % nby;
    const int bm0 = by << 8, bn0 = bx << 7;

    const int tid = threadIdx.x, lane = tid & 63, wave = tid >> 6;
    const int wm = wave >> 1, wn = wave & 1;
    const int l15 = lane & 15, kl = lane >> 4;

    // staging: thread -> 16B granule, rows rh = tid>>3 (0..63 per load);
    // pre-swizzled global source so linear LDS dest + swizzled reads agree.
    const int rh = tid >> 3;
    const int cb_s = (tid & 7) << 4;
    const int kx = (cb_s ^ ((rh & 7) << 4)) >> 1;

    const unsigned short* Abase = A + (size_t)(bm0 + rh) * K + kx;
    const unsigned short* Bbase = BT + (size_t)(bn0 + rh) * K + kx;

    auto stageA = [&](int v, int h) {  // half h = 128 rows = 2 loads
        const unsigned short* g = Abase + (size_t)v * 64 + (size_t)(h * 128) * K;
        char* l = (char*)aL[v & 1] + h * 16384 + tid * 16;
        gload_lds16(g, l);
        gload_lds16(g + (size_t)64 * K, l + 8192);
    };
    auto stageB = [&](int v) {
        const unsigned short* g = Bbase + (size_t)v * 64;
        char* l = (char*)bL[v & 1] + tid * 16;
        gload_lds16(g, l);
        gload_lds16(g + (size_t)64 * K, l + 8192);
    };

    // fragment read addressing (swizzled): row&7 == l15&7 for every frag row
    const int arow = wm * 64 + l15;
    const int brow = wn * 64 + l15;
    const int sa = (l15 & 7) << 4;
    const int ca0 = ((kl * 16) ^ sa) >> 1;
    const int ca1 = ((64 + kl * 16) ^ sa) >> 1;

    f32x4 acc[4][4];
#pragma unroll
    for (int i = 0; i < 4; ++i)
#pragma unroll
        for (int j2 = 0; j2 < 4; ++j2) acc[i][j2] = (f32x4){0.f, 0.f, 0.f, 0.f};

    // prologue: A(0)[4], B(0)[2], B(1)[2]; wait all but newest 2 (B(1) may fly)
    stageA(0, 0); stageA(0, 1); stageB(0); stageB(1);
    asm volatile("s_waitcnt vmcnt(2)" ::: "memory");
    __builtin_amdgcn_s_barrier();

    const int NI = K >> 7;  // 2 K-tiles per iteration
    for (int itI = 0; itI < NI; ++itI) {
        const int u = itI << 1;  // even -> tile u in buf0, u+1 in buf1
        const bool last = (itI == NI - 1);
        const unsigned short* aT0 = aL[0];
        const unsigned short* bT0 = bL[0];
        const unsigned short* aT1 = aL[1];
        const unsigned short* bT1 = bL[1];
        short8 af[2][2], bf[4][2];

        // ph1: tile u: all B + A M0,M1; stage A(u+1) full
        RD_B(bT0);
        RD_A(aT0, 0);
        stageA(u + 1, 0); stageA(u + 1, 1);
        FENCE();
        __builtin_amdgcn_s_barrier();
        MM16(0);
        LGKM0();
        __builtin_amdgcn_s_barrier();

        // ph2: A M2,M3; stage B(u+2); vmcnt gates tile u+1 readiness
        RD_A(aT0, 2);
        if (!last) stageB(u + 2);
        FENCE();
        __builtin_amdgcn_s_barrier();
        MM16(2);
        if (last) { asm volatile("s_waitcnt vmcnt(0)" ::: "memory"); }
        else      { asm volatile("s_waitcnt vmcnt(2)" ::: "memory"); }
        LGKM0();
        __builtin_amdgcn_s_barrier();

        // ph3: tile u+1: all B + A M0,M1; stage A(u+2) h0
        RD_B(bT1);
        RD_A(aT1, 0);
        if (!last) stageA(u + 2, 0);
        FENCE();
        __builtin_amdgcn_s_barrier();
        MM16(0);
        LGKM0();
        __builtin_amdgcn_s_barrier();

        // ph4: A M2,M3; stage A(u+2)h1 + B(u+3); vmcnt gates tile u+2 readiness
        RD_A(aT1, 2);
        if (!last) { stageA(u + 2, 1); stageB(u + 3); }
        FENCE();
        __builtin_amdgcn_s_barrier();
        MM16(2);
        if (!last) { asm volatile("s_waitcnt vmcnt(2)" ::: "memory"); }
        LGKM0();
        __builtin_amdgcn_s_barrier();
    }

    // epilogue
    const int r0 = bm0 + wm * 64 + kl * 4;
    const int c0g = bn0 + wn * 64 + l15;
#pragma unroll
    for (int i = 0; i < 4; ++i) {
#pragma unroll
        for (int j2 = 0; j2 < 4; ++j2) {
            int col = c0g + j2 * 16;
#pragma unroll
            for (int r = 0; r < 4; ++r) {
                int row = r0 + i * 16 + r;
                float v = acc[i][j2][r];
                if constexpr (EPI == 0) {
                    ((unsigned short*)Cout)[(size_t)row * ldc + col] = f2b(v);
                } else if constexpr (EPI == 1) {
                    ((float*)Cout)[(size_t)row * ldc + col] = v;
                } else if constexpr (EPI == 2) {
                    v += bias[col];
                    float t = tanhf(0.7978845608f * (v + 0.044715f * v * v * v));
                    ((unsigned short*)Cout)[(size_t)row * ldc + col] = f2b(0.5f * v * (1.0f + t));
                } else {
                    v += bias[col] + addm[(size_t)row * ldc + col];
                    ((float*)Cout)[(size_t)row * ldc + col] = v;
                }
            }
        }
    }
}

// ---------------- flash attention ----------------
__global__ __launch_bounds__(256, 2) void attn_kernel(const unsigned short* __restrict__ qkv,
                                                      const unsigned short* __restrict__ vT,
                                                      const float* __restrict__ bias,
                                                      unsigned short* __restrict__ attn_vec) {
    __shared__ unsigned short kL[64 * 264];
    __shared__ unsigned short vL[256 * 72];
    __shared__ unsigned short pL[4][16 * 72];

    int qb = blockIdx.x, head = blockIdx.y;
    int tid = threadIdx.x, lane = tid & 63, wave = tid >> 6;
    int q16 = lane & 15, q4 = lane >> 4;

    short8 qf[8];
    {
        const unsigned short* qp =
            qkv + (size_t)(qb * 64 + wave * 16 + q16) * (3 * DM) + head * DHEAD + (q4 << 3);
#pragma unroll
        for (int kk = 0; kk < 8; ++kk) qf[kk] = *(const short8*)(qp + kk * 32);
    }

    f32x4 o[16];
#pragma unroll
    for (int d = 0; d < 16; ++d) o[d] = (f32x4){0.f, 0.f, 0.f, 0.f};
    float m_run[4] = {-INFINITY, -INFINITY, -INFINITY, -INFINITY};
    float l_run[4] = {0.f, 0.f, 0.f, 0.f};
    int qrow0 = qb * 64 + wave * 16 + q4 * 4;

    for (int t = 0; t <= qb; ++t) {
        int kv0 = t * 64;
#pragma unroll
        for (int rr = 0; rr < 8; ++rr) {
            int i = tid + rr * 256;
            int row = i >> 5, c8 = (i & 31) << 3;
            *(ushort8v*)(kL + row * 264 + c8) =
                *(const ushort8v*)(qkv + (size_t)(kv0 + row) * (3 * DM) + DM + head * DHEAD + c8);
        }
#pragma unroll
        for (int rr = 0; rr < 8; ++rr) {
            int i = tid + rr * 256;
            int d = i >> 3, c8 = (i & 7) << 3;
            *(ushort8v*)(vL + d * 72 + c8) =
                *(const ushort8v*)(vT + (size_t)(head * DHEAD + d) * SEQ + kv0 + c8);
        }
        __syncthreads();

        f32x4 s[4];
#pragma unroll
        for (int c = 0; c < 4; ++c) s[c] = (f32x4){0.f, 0.f, 0.f, 0.f};
#pragma unroll
        for (int kk = 0; kk < 8; ++kk) {
#pragma unroll
            for (int c = 0; c < 4; ++c) {
                short8 kf = *(const short8*)(kL + (c * 16 + q16) * 264 + kk * 32 + (q4 << 3));
                s[c] = __builtin_amdgcn_mfma_f32_16x16x32_bf16(qf[kk], kf, s[c], 0, 0, 0);
            }
        }

        bool diag = (t == qb);
#pragma unroll
        for (int r = 0; r < 4; ++r) {
            int qr = qrow0 + r;
            float sv[4];
#pragma unroll
            for (int c = 0; c < 4; ++c) {
                float vv = s[c][r] * 0.0625f + bias[(size_t)qr * SEQ + kv0 + c * 16 + q16];
                if (diag && (kv0 + c * 16 + q16) > qr) vv = -1e30f;
                sv[c] = vv;
            }
            float m = fmaxf(fmaxf(sv[0], sv[1]), fmaxf(sv[2], sv[3]));
#pragma unroll
            for (int off = 1; off < 16; off <<= 1) m = fmaxf(m, __shfl_xor(m, off));
            float mn = fmaxf(m_run[r], m);
            float alpha = __expf(m_run[r] - mn);
            float psum = 0.f;
#pragma unroll
            for (int c = 0; c < 4; ++c) {
                float p = __expf(sv[c] - mn);
                psum += p;
                pL[wave][(q4 * 4 + r) * 72 + c * 16 + q16] = f2b(p);
            }
#pragma unroll
            for (int off = 1; off < 16; off <<= 1) psum += __shfl_xor(psum, off);
            l_run[r] = l_run[r] * alpha + psum;
            m_run[r] = mn;
#pragma unroll
            for (int d = 0; d < 16; ++d) o[d][r] *= alpha;
        }

#pragma unroll
        for (int ks = 0; ks < 2; ++ks) {
            short8 pa = *(const short8*)(pL[wave] + q16 * 72 + ks * 32 + (q4 << 3));
#pragma unroll
            for (int d = 0; d < 16; ++d) {
                short8 vb = *(const short8*)(vL + (d * 16 + q16) * 72 + ks * 32 + (q4 << 3));
                o[d] = __builtin_amdgcn_mfma_f32_16x16x32_bf16(pa, vb, o[d], 0, 0, 0);
            }
        }
        __syncthreads();
    }

#pragma unroll
    for (int r = 0; r < 4; ++r) {
        float inv = 1.0f / l_run[r];
#pragma unroll
        for (int d = 0; d < 16; ++d)
            attn_vec[(size_t)(qrow0 + r) * DM + head * DHEAD + d * 16 + q16] = f2b(o[d][r] * inv);
    }
}

// ---------------- launch ----------------
extern "C" void kernel_launch(void* const* d_in, const int* in_sizes, int n_in,
                              void* d_out, int out_size, void* d_ws, size_t ws_size,
                              hipStream_t stream) {
    const float* x = (const float*)d_in[0];
    const float* attn_bias = (const float*)d_in[1];
    const float* ln_scale = (const float*)d_in[2];
    const float* ln_offset = (const float*)d_in[3];
    const float* wq = (const float*)d_in[4];
    const float* wk = (const float*)d_in[5];
    const float* wv = (const float*)d_in[6];
    const float* wo = (const float*)d_in[7];
    const float* w_ffn = (const float*)d_in[8];
    const float* b_ffn = (const float*)d_in[9];
    const float* w_ffn_o = (const float*)d_in[10];
    const float* b_ffn_o = (const float*)d_in[11];
    float* out = (float*)d_out;

    char* p = (char*)d_ws;
    unsigned short* WT_qkv = (unsigned short*)p; p += (size_t)3 * DM * DM * 2;
    unsigned short* WT_o = (unsigned short*)p;   p += (size_t)DM * DM * 2;
    unsigned short* WT_f1 = (unsigned short*)p;  p += (size_t)DFF * DM * 2;
    unsigned short* WT_f2 = (unsigned short*)p;  p += (size_t)DM * DFF * 2;
    unsigned short* hB = (unsigned short*)p;     p += (size_t)SEQ * DM * 2;
    unsigned short* qkvB = (unsigned short*)p;   p += (size_t)SEQ * 3 * DM * 2;
    unsigned short* vTB = (unsigned short*)p;    p += (size_t)DM * SEQ * 2;
    unsigned short* avB = (unsigned short*)p;    p += (size_t)SEQ * DM * 2;
    float* attn_out = (float*)p;                 p += (size_t)SEQ * DM * 4;
    unsigned short* ffB = (unsigned short*)p;    p += (size_t)SEQ * DFF * 2;

    transpose_cvt<float><<<dim3(DM / 64, DM / 64), 256, 0, stream>>>(wq, WT_qkv, DM, DM, DM, DM);
    transpose_cvt<float><<<dim3(DM / 64, DM / 64), 256, 0, stream>>>(wk, WT_qkv + (size_t)DM * DM, DM, DM, DM, DM);
    transpose_cvt<float><<<dim3(DM / 64, DM / 64), 256, 0, stream>>>(wv, WT_qkv + (size_t)2 * DM * DM, DM, DM, DM, DM);
    transpose_cvt<float><<<dim3(DM / 64, DM / 64), 256, 0, stream>>>(wo, WT_o, DM, DM, DM, DM);
    transpose_cvt<float><<<dim3(DFF / 64, DM / 64), 256, 0, stream>>>(w_ffn, WT_f1, DFF, DM, DM, DFF);
    transpose_cvt<float><<<dim3(DM / 64, DFF / 64), 256, 0, stream>>>(w_ffn_o, WT_f2, DM, DFF, DFF, DM);

    ln_kernel<<<SEQ, 256, 0, stream>>>(x, ln_scale, ln_offset, hB);

    // QKV: nby=8, nbx=96 -> 768 blocks (3 rounds of 256)
    gemm8p<0><<<(SEQ / 256) * (3 * DM / 128), 512, 0, stream>>>(hB, WT_qkv, qkvB, SEQ, 3 * DM, DM, 3 * DM, nullptr, nullptr);
    transpose_cvt<unsigned short><<<dim3(DM / 64, SEQ / 64), 256, 0, stream>>>(qkvB + 2 * DM, vTB, 3 * DM, SEQ, SEQ, DM);

    attn_kernel<<<dim3(SEQ / 64, NHEADS), 256, 0, stream>>>(qkvB, vTB, attn_bias, avB);

    // WO: 8x32 = 256 blocks (1/CU exact)
    gemm8p<1><<<(SEQ / 256) * (DM / 128), 512, 0, stream>>>(avB, WT_o, attn_out, SEQ, DM, DM, DM, nullptr, nullptr);
    // FFN1: 8x128 = 1024 blocks (4 rounds)
    gemm8p<2><<<(SEQ / 256) * (DFF / 128), 512, 0, stream>>>(hB, WT_f1, ffB, SEQ, DFF, DM, DFF, b_ffn, nullptr);
    // FFN2: 8x32 = 256 blocks (1/CU exact), K=16384
    gemm8p<3><<<(SEQ / 256) * (DM / 128), 512, 0, stream>>>(ffB, WT_f2, out, SEQ, DM, DFF, DM, b_ffn_o, attn_out);
}

// Round 7
// 1284.004 us; speedup vs baseline: 1.1705x; 1.1511x over previous
//
#include <hip/hip_runtime.h>
#include <stdint.h>

#define SEQ 2048
#define DM 4096
#define NHEADS 16
#define DHEAD 256
#define DFF 16384

typedef __attribute__((ext_vector_type(8))) short short8;
typedef __attribute__((ext_vector_type(4))) float f32x4;
typedef __attribute__((ext_vector_type(4))) float float4v;
typedef __attribute__((ext_vector_type(4))) unsigned short ushort4v;
typedef __attribute__((ext_vector_type(8))) unsigned short ushort8v;

__device__ __forceinline__ unsigned short f2b(float f) {
    uint32_t u = __builtin_bit_cast(uint32_t, f);
    u = (u + 0x7FFFu + ((u >> 16) & 1u)) >> 16;
    return (unsigned short)u;
}

__device__ __forceinline__ void gload_lds16(const void* g, void* l) {
    __builtin_amdgcn_global_load_lds((const __attribute__((address_space(1))) void*)g,
                                     (__attribute__((address_space(3))) void*)l, 16, 0, 0);
}

// ---------------- transpose + (optional f32->bf16) convert ----------------
template <typename T>
__global__ __launch_bounds__(256) void transpose_cvt(const T* __restrict__ src,
                                                     unsigned short* __restrict__ dst,
                                                     int ldS, int ldD, int R, int C) {
    __shared__ unsigned short tl[64 * 66];
    int r0 = blockIdx.y << 6, c0 = blockIdx.x << 6;
    int tid = threadIdx.x;
#pragma unroll
    for (int it = 0; it < 4; ++it) {
        int e = (tid + it * 256) * 4;
        int rr = e >> 6, cc = e & 63;
        const T* sp = src + (size_t)(r0 + rr) * ldS + c0 + cc;
        if constexpr (sizeof(T) == 4) {
            float4v v = *(const float4v*)sp;
#pragma unroll
            for (int j = 0; j < 4; ++j) tl[rr * 66 + cc + j] = f2b(v[j]);
        } else {
            ushort4v v = *(const ushort4v*)sp;
#pragma unroll
            for (int j = 0; j < 4; ++j) tl[rr * 66 + cc + j] = v[j];
        }
    }
    __syncthreads();
#pragma unroll
    for (int it = 0; it < 2; ++it) {
        int e = tid + it * 256;
        int oc = e >> 3;
        int k8 = (e & 7) * 8;
        ushort8v w;
#pragma unroll
        for (int j = 0; j < 8; ++j) w[j] = tl[(k8 + j) * 66 + oc];
        *(ushort8v*)(dst + (size_t)(c0 + oc) * ldD + r0 + k8) = w;
    }
}

// ---------------- LayerNorm ----------------
__global__ __launch_bounds__(256) void ln_kernel(const float* __restrict__ x,
                                                 const float* __restrict__ sc,
                                                 const float* __restrict__ of,
                                                 unsigned short* __restrict__ h) {
    int row = blockIdx.x;
    int tid = threadIdx.x, lane = tid & 63, wave = tid >> 6;
    const float4v* xr = (const float4v*)(x + (size_t)row * DM);
    float4v v[4];
    float s = 0.f, s2 = 0.f;
#pragma unroll
    for (int i = 0; i < 4; ++i) {
        v[i] = xr[tid + i * 256];
#pragma unroll
        for (int j = 0; j < 4; ++j) { s += v[i][j]; s2 += v[i][j] * v[i][j]; }
    }
#pragma unroll
    for (int o = 1; o < 64; o <<= 1) { s += __shfl_xor(s, o); s2 += __shfl_xor(s2, o); }
    __shared__ float rs[4], rs2[4];
    if (lane == 0) { rs[wave] = s; rs2[wave] = s2; }
    __syncthreads();
    s = rs[0] + rs[1] + rs[2] + rs[3];
    s2 = rs2[0] + rs2[1] + rs2[2] + rs2[3];
    float mean = s * (1.0f / DM);
    float var = s2 * (1.0f / DM) - mean * mean;
    float inv = rsqrtf(var + 1e-5f);
#pragma unroll
    for (int i = 0; i < 4; ++i) {
        int c = (tid + i * 256) * 4;
        ushort4v o4;
#pragma unroll
        for (int j = 0; j < 4; ++j)
            o4[j] = f2b((v[i][j] - mean) * inv * sc[c + j] + of[c + j]);
        *(ushort4v*)(h + (size_t)row * DM + c) = o4;
    }
}

// ---------------- 256x256 8-phase GEMM: C[M,N] = A[M,K](bf16) * BT[N,K]^T ----------------
// m201 geometry: BM=BN=256, BK=64, 512 thr (8 waves 2Mx4N, per-wave 128x64 -> acc[8][4]).
// LDS 128KiB (2dbuf x (A 32KB + B 32KB)), 1 blk/CU. 8 phases per 2 K-tiles, 16 MFMA/phase,
// snake quadrant order (B registers stay live across a K-tile -> minimal 24 ds_read_b128/wave).
// 1 half-tile (2 gload_lds) staged per phase: ph1,2=A(u+1); ph3,4=B(u+2); ph5,6=A(u+2);
// ph7,8=B(u+3). WAR-safe: A halves private to wm, B 64-row bands private to wn; all reads of
// a buffer complete >=1 phase before its overwrite. vmcnt(4) at ph4/ph8 only (4 = loads issued
// after gating tile's last half). XOR swizzle (row&7)<<4 via pre-swizzled source (conflicts=0,
// verified r2-r6). Column-slab XCD map. SPLIT=2: K halved per block, f32 partials at Cout+s*M*N.
#define MF(a, b, c) __builtin_amdgcn_mfma_f32_16x16x32_bf16(a, b, c, 0, 0, 0)
#define FENCE() asm volatile("" ::: "memory")
#define LGKM0() asm volatile("s_waitcnt lgkmcnt(0)" ::: "memory")
#define BARR() __builtin_amdgcn_s_barrier()

#define RDA(BUF, MB)                                                                     \
    _Pragma("unroll") for (int i2 = 0; i2 < 4; ++i2) {                                   \
        af[i2][0] = *(const short8*)((BUF) + (arowb + ((MB) + i2) * 16) * 64 + ca0);     \
        af[i2][1] = *(const short8*)((BUF) + (arowb + ((MB) + i2) * 16) * 64 + ca1);     \
    }
#define RDB(BUF, NB)                                                                     \
    _Pragma("unroll") for (int j2 = 0; j2 < 2; ++j2) {                                   \
        bf[(NB) + j2][0] = *(const short8*)((BUF) + (brow + ((NB) + j2) * 16) * 64 + ca0);\
        bf[(NB) + j2][1] = *(const short8*)((BUF) + (brow + ((NB) + j2) * 16) * 64 + ca1);\
    }
#define MMQ(MB, NB)                                                                      \
    __builtin_amdgcn_s_setprio(1);                                                       \
    _Pragma("unroll") for (int kk = 0; kk < 2; ++kk)                                     \
        _Pragma("unroll") for (int i2 = 0; i2 < 4; ++i2)                                 \
            _Pragma("unroll") for (int j2 = 0; j2 < 2; ++j2)                             \
                acc[(MB) + i2][(NB) + j2] =                                              \
                    MF(af[i2][kk], bf[(NB) + j2][kk], acc[(MB) + i2][(NB) + j2]);        \
    __builtin_amdgcn_s_setprio(0)

template <int EPI, int SPLIT>
__global__ __launch_bounds__(512, 1) void gemm2sq(const unsigned short* __restrict__ A,
                                                  const unsigned short* __restrict__ BT,
                                                  void* __restrict__ Cout,
                                                  int M, int N, int Kfull, int ldc,
                                                  const float* __restrict__ bias) {
    __shared__ unsigned short aL[2][256 * 64];  // 64 KB
    __shared__ unsigned short bL[2][256 * 64];  // 64 KB

    const int nby = M >> 8, nbx = N >> 8;
    const int nwg = nby * nbx;
    int b = blockIdx.x;
    int sp = 0;
    if (SPLIT == 2) { sp = (b >= nwg) ? 1 : 0; b -= sp * nwg; }
    const int Keff = Kfull / SPLIT;
    const int koff = sp * Keff;

    const int slabw = nbx >> 3;
    const int xcd = b & 7;
    const int jj = b >> 3;
    const int bx = xcd * slabw + jj / nby;
    const int by = jj % nby;
    const int bm0 = by << 8, bn0 = bx << 8;

    const int tid = threadIdx.x, lane = tid & 63, wave = tid >> 6;
    const int wm = wave >> 2, wn = wave & 3;
    const int l15 = lane & 15, kl = lane >> 4;

    // staging: thread -> 16B granule; pre-swizzled source, linear LDS dest
    const int rh = tid >> 3;
    const int cb_s = (tid & 7) << 4;
    const int kx = (cb_s ^ ((rh & 7) << 4)) >> 1;

    const unsigned short* Abase = A + (size_t)(bm0 + rh) * Kfull + koff + kx;
    const unsigned short* Bbase = BT + (size_t)(bn0 + rh) * Kfull + koff + kx;

    auto stageA = [&](int v, int h) {  // half h: rows h*128..h*128+127
        const unsigned short* g = Abase + (size_t)v * 64 + (size_t)(h * 128) * Kfull;
        char* l = (char*)aL[v & 1] + h * 16384 + tid * 16;
        gload_lds16(g, l);
        gload_lds16(g + (size_t)64 * Kfull, l + 8192);
    };
    auto stageB = [&](int v, int h) {
        const unsigned short* g = Bbase + (size_t)v * 64 + (size_t)(h * 128) * Kfull;
        char* l = (char*)bL[v & 1] + h * 16384 + tid * 16;
        gload_lds16(g, l);
        gload_lds16(g + (size_t)64 * Kfull, l + 8192);
    };

    // fragment read addressing (swizzled): row&7 == l15&7 for all frag rows
    const int arowb = wm * 128 + l15;
    const int brow = wn * 64 + l15;
    const int sa = (l15 & 7) << 4;
    const int ca0 = ((kl * 16) ^ sa) >> 1;
    const int ca1 = ((64 + kl * 16) ^ sa) >> 1;

    f32x4 acc[8][4];
#pragma unroll
    for (int i = 0; i < 8; ++i)
#pragma unroll
        for (int j2 = 0; j2 < 4; ++j2) acc[i][j2] = (f32x4){0.f, 0.f, 0.f, 0.f};

    short8 af[4][2], bf[4][2];

    // prologue: tile0 (A,B) + B(1); wait tile0 (B(1)'s 4 loads stay in flight)
    stageA(0, 0); stageA(0, 1); stageB(0, 0); stageB(0, 1); stageB(1, 0); stageB(1, 1);
    asm volatile("s_waitcnt vmcnt(4)" ::: "memory");
    BARR();

    const int NI = (Keff >> 6) >> 1;  // iterations of 2 K-tiles
    for (int t2 = 0; t2 < NI; ++t2) {
        const int u = t2 << 1;
        const bool last = (t2 == NI - 1);
        const unsigned short* a0 = aL[0];
        const unsigned short* b0 = bL[0];
        const unsigned short* a1 = aL[1];
        const unsigned short* b1 = bL[1];

        // ph1: tile u: A0-3, B01
        RDA(a0, 0); RDB(b0, 0);
        stageA(u + 1, 0);
        FENCE(); BARR();
        MMQ(0, 0);
        LGKM0(); BARR();
        // ph2: B23 (A0-3 live)
        RDB(b0, 2);
        stageA(u + 1, 1);
        FENCE(); BARR();
        MMQ(0, 2);
        LGKM0(); BARR();
        // ph3: A4-7 (B01 live)
        RDA(a0, 4);
        if (!last) stageB(u + 2, 0);
        FENCE(); BARR();
        MMQ(4, 0);
        LGKM0(); BARR();
        // ph4: (all live) — vmcnt gates tile u+1
        if (!last) stageB(u + 2, 1);
        FENCE(); BARR();
        MMQ(4, 2);
        if (last) { asm volatile("s_waitcnt vmcnt(0)" ::: "memory"); }
        else      { asm volatile("s_waitcnt vmcnt(4)" ::: "memory"); }
        LGKM0(); BARR();

        // ph5: tile u+1: A0-3, B01
        RDA(a1, 0); RDB(b1, 0);
        if (!last) stageA(u + 2, 0);
        FENCE(); BARR();
        MMQ(0, 0);
        LGKM0(); BARR();
        // ph6: B23
        RDB(b1, 2);
        if (!last) stageA(u + 2, 1);
        FENCE(); BARR();
        MMQ(0, 2);
        LGKM0(); BARR();
        // ph7: A4-7
        RDA(a1, 4);
        if (!last) stageB(u + 3, 0);
        FENCE(); BARR();
        MMQ(4, 0);
        LGKM0(); BARR();
        // ph8: vmcnt gates tile u+2
        if (!last) stageB(u + 3, 1);
        FENCE(); BARR();
        MMQ(4, 2);
        if (!last) { asm volatile("s_waitcnt vmcnt(4)" ::: "memory"); }
        LGKM0(); BARR();
    }

    // epilogue
    const int r0 = bm0 + wm * 128 + kl * 4;
    const int c0g = bn0 + wn * 64 + l15;
#pragma unroll
    for (int mi = 0; mi < 8; ++mi) {
#pragma unroll
        for (int nj = 0; nj < 4; ++nj) {
            int col = c0g + nj * 16;
#pragma unroll
            for (int r = 0; r < 4; ++r) {
                int row = r0 + mi * 16 + r;
                float v = acc[mi][nj][r];
                if constexpr (EPI == 0) {
                    ((unsigned short*)Cout)[(size_t)row * ldc + col] = f2b(v);
                } else if constexpr (EPI == 1) {
                    ((float*)Cout)[(size_t)sp * M * N + (size_t)row * ldc + col] = v;
                } else {
                    v += bias[col];
                    float t = tanhf(0.7978845608f * (v + 0.044715f * v * v * v));
                    ((unsigned short*)Cout)[(size_t)row * ldc + col] = f2b(0.5f * v * (1.0f + t));
                }
            }
        }
    }
}

// ---------------- final reduce: out = fp0+fp1 + wp0+wp1 + b_ffn_o ----------------
__global__ __launch_bounds__(256) void final_reduce(const float* __restrict__ fp,
                                                    const float* __restrict__ wp,
                                                    const float* __restrict__ bias,
                                                    float* __restrict__ out) {
    size_t i = (size_t)blockIdx.x * 256 + threadIdx.x;  // float4 index
    const float4v* f0 = (const float4v*)fp;
    const float4v* f1 = (const float4v*)(fp + (size_t)SEQ * DM);
    const float4v* w0 = (const float4v*)wp;
    const float4v* w1 = (const float4v*)(wp + (size_t)SEQ * DM);
    const float4v* b4 = (const float4v*)bias;
    float4v v = f0[i] + f1[i] + w0[i] + w1[i] + b4[i & (DM / 4 - 1)];
    ((float4v*)out)[i] = v;
}

// ---------------- flash attention ----------------
__global__ __launch_bounds__(256, 2) void attn_kernel(const unsigned short* __restrict__ qkv,
                                                      const unsigned short* __restrict__ vT,
                                                      const float* __restrict__ bias,
                                                      unsigned short* __restrict__ attn_vec) {
    __shared__ unsigned short kL[64 * 264];
    __shared__ unsigned short vL[256 * 72];
    __shared__ unsigned short pL[4][16 * 72];

    int qb = blockIdx.x, head = blockIdx.y;
    int tid = threadIdx.x, lane = tid & 63, wave = tid >> 6;
    int q16 = lane & 15, q4 = lane >> 4;

    short8 qf[8];
    {
        const unsigned short* qp =
            qkv + (size_t)(qb * 64 + wave * 16 + q16) * (3 * DM) + head * DHEAD + (q4 << 3);
#pragma unroll
        for (int kk = 0; kk < 8; ++kk) qf[kk] = *(const short8*)(qp + kk * 32);
    }

    f32x4 o[16];
#pragma unroll
    for (int d = 0; d < 16; ++d) o[d] = (f32x4){0.f, 0.f, 0.f, 0.f};
    float m_run[4] = {-INFINITY, -INFINITY, -INFINITY, -INFINITY};
    float l_run[4] = {0.f, 0.f, 0.f, 0.f};
    int qrow0 = qb * 64 + wave * 16 + q4 * 4;

    for (int t = 0; t <= qb; ++t) {
        int kv0 = t * 64;
#pragma unroll
        for (int rr = 0; rr < 8; ++rr) {
            int i = tid + rr * 256;
            int row = i >> 5, c8 = (i & 31) << 3;
            *(ushort8v*)(kL + row * 264 + c8) =
                *(const ushort8v*)(qkv + (size_t)(kv0 + row) * (3 * DM) + DM + head * DHEAD + c8);
        }
#pragma unroll
        for (int rr = 0; rr < 8; ++rr) {
            int i = tid + rr * 256;
            int d = i >> 3, c8 = (i & 7) << 3;
            *(ushort8v*)(vL + d * 72 + c8) =
                *(const ushort8v*)(vT + (size_t)(head * DHEAD + d) * SEQ + kv0 + c8);
        }
        __syncthreads();

        f32x4 s[4];
#pragma unroll
        for (int c = 0; c < 4; ++c) s[c] = (f32x4){0.f, 0.f, 0.f, 0.f};
#pragma unroll
        for (int kk = 0; kk < 8; ++kk) {
#pragma unroll
            for (int c = 0; c < 4; ++c) {
                short8 kf = *(const short8*)(kL + (c * 16 + q16) * 264 + kk * 32 + (q4 << 3));
                s[c] = __builtin_amdgcn_mfma_f32_16x16x32_bf16(qf[kk], kf, s[c], 0, 0, 0);
            }
        }

        bool diag = (t == qb);
#pragma unroll
        for (int r = 0; r < 4; ++r) {
            int qr = qrow0 + r;
            float sv[4];
#pragma unroll
            for (int c = 0; c < 4; ++c) {
                float vv = s[c][r] * 0.0625f + bias[(size_t)qr * SEQ + kv0 + c * 16 + q16];
                if (diag && (kv0 + c * 16 + q16) > qr) vv = -1e30f;
                sv[c] = vv;
            }
            float m = fmaxf(fmaxf(sv[0], sv[1]), fmaxf(sv[2], sv[3]));
#pragma unroll
            for (int off = 1; off < 16; off <<= 1) m = fmaxf(m, __shfl_xor(m, off));
            float mn = fmaxf(m_run[r], m);
            float alpha = __expf(m_run[r] - mn);
            float psum = 0.f;
#pragma unroll
            for (int c = 0; c < 4; ++c) {
                float p = __expf(sv[c] - mn);
                psum += p;
                pL[wave][(q4 * 4 + r) * 72 + c * 16 + q16] = f2b(p);
            }
#pragma unroll
            for (int off = 1; off < 16; off <<= 1) psum += __shfl_xor(psum, off);
            l_run[r] = l_run[r] * alpha + psum;
            m_run[r] = mn;
#pragma unroll
            for (int d = 0; d < 16; ++d) o[d][r] *= alpha;
        }

#pragma unroll
        for (int ks = 0; ks < 2; ++ks) {
            short8 pa = *(const short8*)(pL[wave] + q16 * 72 + ks * 32 + (q4 << 3));
#pragma unroll
            for (int d = 0; d < 16; ++d) {
                short8 vb = *(const short8*)(vL + (d * 16 + q16) * 72 + ks * 32 + (q4 << 3));
                o[d] = __builtin_amdgcn_mfma_f32_16x16x32_bf16(pa, vb, o[d], 0, 0, 0);
            }
        }
        __syncthreads();
    }

#pragma unroll
    for (int r = 0; r < 4; ++r) {
        float inv = 1.0f / l_run[r];
#pragma unroll
        for (int d = 0; d < 16; ++d)
            attn_vec[(size_t)(qrow0 + r) * DM + head * DHEAD + d * 16 + q16] = f2b(o[d][r] * inv);
    }
}

// ---------------- launch ----------------
extern "C" void kernel_launch(void* const* d_in, const int* in_sizes, int n_in,
                              void* d_out, int out_size, void* d_ws, size_t ws_size,
                              hipStream_t stream) {
    const float* x = (const float*)d_in[0];
    const float* attn_bias = (const float*)d_in[1];
    const float* ln_scale = (const float*)d_in[2];
    const float* ln_offset = (const float*)d_in[3];
    const float* wq = (const float*)d_in[4];
    const float* wk = (const float*)d_in[5];
    const float* wv = (const float*)d_in[6];
    const float* wo = (const float*)d_in[7];
    const float* w_ffn = (const float*)d_in[8];
    const float* b_ffn = (const float*)d_in[9];
    const float* w_ffn_o = (const float*)d_in[10];
    const float* b_ffn_o = (const float*)d_in[11];
    float* out = (float*)d_out;

    char* p = (char*)d_ws;
    unsigned short* WT_qkv = (unsigned short*)p; p += (size_t)3 * DM * DM * 2;   // 96MB
    unsigned short* WT_o = (unsigned short*)p;   p += (size_t)DM * DM * 2;       // 32MB
    unsigned short* WT_f1 = (unsigned short*)p;  p += (size_t)DFF * DM * 2;      // 128MB
    unsigned short* WT_f2 = (unsigned short*)p;  p += (size_t)DM * DFF * 2;      // 128MB
    unsigned short* hB = (unsigned short*)p;     p += (size_t)SEQ * DM * 2;
    unsigned short* qkvB = (unsigned short*)p;   p += (size_t)SEQ * 3 * DM * 2;
    unsigned short* vTB = (unsigned short*)p;    p += (size_t)DM * SEQ * 2;
    unsigned short* avB = (unsigned short*)p;    p += (size_t)SEQ * DM * 2;
    unsigned short* ffB = (unsigned short*)p;    p += (size_t)SEQ * DFF * 2;

    // split-K partial buffers ALIAS dead weight buffers (safe: fp written by FFN2 which runs
    // after QKV consumed WT_qkv; wp written by WO which runs after FFN1 consumed WT_f1).
    float* fp = (float*)WT_qkv;  // 2 x SEQ x DM f32 = 64MB <= 96MB
    float* wp = (float*)WT_f1;   // 2 x SEQ x DM f32 = 64MB <= 128MB

    transpose_cvt<float><<<dim3(DM / 64, DM / 64), 256, 0, stream>>>(wq, WT_qkv, DM, DM, DM, DM);
    transpose_cvt<float><<<dim3(DM / 64, DM / 64), 256, 0, stream>>>(wk, WT_qkv + (size_t)DM * DM, DM, DM, DM, DM);
    transpose_cvt<float><<<dim3(DM / 64, DM / 64), 256, 0, stream>>>(wv, WT_qkv + (size_t)2 * DM * DM, DM, DM, DM, DM);
    transpose_cvt<float><<<dim3(DM / 64, DM / 64), 256, 0, stream>>>(wo, WT_o, DM, DM, DM, DM);
    transpose_cvt<float><<<dim3(DFF / 64, DM / 64), 256, 0, stream>>>(w_ffn, WT_f1, DFF, DM, DM, DFF);
    transpose_cvt<float><<<dim3(DM / 64, DFF / 64), 256, 0, stream>>>(w_ffn_o, WT_f2, DM, DFF, DFF, DM);

    ln_kernel<<<SEQ, 256, 0, stream>>>(x, ln_scale, ln_offset, hB);

    // QKV: 8x48 = 384 blocks
    gemm2sq<0, 1><<<(SEQ / 256) * (3 * DM / 256), 512, 0, stream>>>(hB, WT_qkv, qkvB, SEQ, 3 * DM, DM, 3 * DM, nullptr);
    transpose_cvt<unsigned short><<<dim3(DM / 64, SEQ / 64), 256, 0, stream>>>(qkvB + 2 * DM, vTB, 3 * DM, SEQ, SEQ, DM);

    attn_kernel<<<dim3(SEQ / 64, NHEADS), 256, 0, stream>>>(qkvB, vTB, attn_bias, avB);

    // FFN1: 8x64 = 512 blocks (before WO so wp can alias WT_f1)
    gemm2sq<2, 1><<<(SEQ / 256) * (DFF / 256), 512, 0, stream>>>(hB, WT_f1, ffB, SEQ, DFF, DM, DFF, b_ffn);
    // WO split-K=2: 2 x (8x16) = 256 blocks -> wp partials
    gemm2sq<1, 2><<<2 * (SEQ / 256) * (DM / 256), 512, 0, stream>>>(avB, WT_o, wp, SEQ, DM, DM, DM, nullptr);
    // FFN2 split-K=2: 256 blocks -> fp partials
    gemm2sq<1, 2><<<2 * (SEQ / 256) * (DM / 256), 512, 0, stream>>>(ffB, WT_f2, fp, SEQ, DM, DFF, DM, nullptr);
    // out = fp0+fp1 + wp0+wp1 + b_ffn_o
    final_reduce<<<(SEQ * DM / 4) / 256, 256, 0, stream>>>(fp, wp, b_ffn_o, out);
}

// Round 8
// 1248.973 us; speedup vs baseline: 1.2033x; 1.0280x over previous
//
#include <hip/hip_runtime.h>
#include <stdint.h>

#define SEQ 2048
#define DM 4096
#define NHEADS 16
#define DHEAD 256
#define DFF 16384

typedef __attribute__((ext_vector_type(8))) short short8;
typedef __attribute__((ext_vector_type(4))) float f32x4;
typedef __attribute__((ext_vector_type(4))) float float4v;
typedef __attribute__((ext_vector_type(4))) unsigned short ushort4v;
typedef __attribute__((ext_vector_type(8))) unsigned short ushort8v;

__device__ __forceinline__ unsigned short f2b(float f) {
    uint32_t u = __builtin_bit_cast(uint32_t, f);
    u = (u + 0x7FFFu + ((u >> 16) & 1u)) >> 16;
    return (unsigned short)u;
}

__device__ __forceinline__ void gload_lds16(const void* g, void* l) {
    __builtin_amdgcn_global_load_lds((const __attribute__((address_space(1))) void*)g,
                                     (__attribute__((address_space(3))) void*)l, 16, 0, 0);
}

// ---------------- transpose + (optional f32->bf16) convert ----------------
template <typename T>
__global__ __launch_bounds__(256) void transpose_cvt(const T* __restrict__ src,
                                                     unsigned short* __restrict__ dst,
                                                     int ldS, int ldD, int R, int C) {
    __shared__ unsigned short tl[64 * 66];
    int r0 = blockIdx.y << 6, c0 = blockIdx.x << 6;
    int tid = threadIdx.x;
#pragma unroll
    for (int it = 0; it < 4; ++it) {
        int e = (tid + it * 256) * 4;
        int rr = e >> 6, cc = e & 63;
        const T* sp = src + (size_t)(r0 + rr) * ldS + c0 + cc;
        if constexpr (sizeof(T) == 4) {
            float4v v = *(const float4v*)sp;
#pragma unroll
            for (int j = 0; j < 4; ++j) tl[rr * 66 + cc + j] = f2b(v[j]);
        } else {
            ushort4v v = *(const ushort4v*)sp;
#pragma unroll
            for (int j = 0; j < 4; ++j) tl[rr * 66 + cc + j] = v[j];
        }
    }
    __syncthreads();
#pragma unroll
    for (int it = 0; it < 2; ++it) {
        int e = tid + it * 256;
        int oc = e >> 3;
        int k8 = (e & 7) * 8;
        ushort8v w;
#pragma unroll
        for (int j = 0; j < 8; ++j) w[j] = tl[(k8 + j) * 66 + oc];
        *(ushort8v*)(dst + (size_t)(c0 + oc) * ldD + r0 + k8) = w;
    }
}

// ---------------- LayerNorm ----------------
__global__ __launch_bounds__(256) void ln_kernel(const float* __restrict__ x,
                                                 const float* __restrict__ sc,
                                                 const float* __restrict__ of,
                                                 unsigned short* __restrict__ h) {
    int row = blockIdx.x;
    int tid = threadIdx.x, lane = tid & 63, wave = tid >> 6;
    const float4v* xr = (const float4v*)(x + (size_t)row * DM);
    float4v v[4];
    float s = 0.f, s2 = 0.f;
#pragma unroll
    for (int i = 0; i < 4; ++i) {
        v[i] = xr[tid + i * 256];
#pragma unroll
        for (int j = 0; j < 4; ++j) { s += v[i][j]; s2 += v[i][j] * v[i][j]; }
    }
#pragma unroll
    for (int o = 1; o < 64; o <<= 1) { s += __shfl_xor(s, o); s2 += __shfl_xor(s2, o); }
    __shared__ float rs[4], rs2[4];
    if (lane == 0) { rs[wave] = s; rs2[wave] = s2; }
    __syncthreads();
    s = rs[0] + rs[1] + rs[2] + rs[3];
    s2 = rs2[0] + rs2[1] + rs2[2] + rs2[3];
    float mean = s * (1.0f / DM);
    float var = s2 * (1.0f / DM) - mean * mean;
    float inv = rsqrtf(var + 1e-5f);
#pragma unroll
    for (int i = 0; i < 4; ++i) {
        int c = (tid + i * 256) * 4;
        ushort4v o4;
#pragma unroll
        for (int j = 0; j < 4; ++j)
            o4[j] = f2b((v[i][j] - mean) * inv * sc[c + j] + of[c + j]);
        *(ushort4v*)(h + (size_t)row * DM + c) = o4;
    }
}

// ---------------- 256x256 8-phase GEMM w/ register lookahead ----------------
// r7 geometry (BM=BN=256, BK=64, 8 waves 2Mx4N, per-wave 128x64, LDS 128KiB, 1 blk/CU)
// + r8: whole-tile fragment reads front-loaded (ph1: A0-3+B all, ph2: A4-7; ph3/ph4 zero
// ds_reads) so only the vmcnt-gated phases (ph1/ph5) pay LDS read latency; other phases'
// MFMAs consume landed registers. Stages: A(u+1)@ph1,2; B(u+2)@ph3,4; A(u+2)@ph5,6;
// B(u+3)@ph7,8. WAR: buf0-B read ph1, staged ph3; buf0-A read ph2, staged ph5 (all >=1
// phase + barrier apart). vmcnt(4) at ph4/ph8 only. XOR swizzle (row&7)<<4 pre-swizzled
// source (conflicts=0, verified r2-r7). Column-slab XCD map. Runtime epi; dual param set
// (merged QKV+FFN1 launch); SPLIT=2 -> f32 partials at C + sp*M*N.
#define MF(a, b, c) __builtin_amdgcn_mfma_f32_16x16x32_bf16(a, b, c, 0, 0, 0)
#define FENCE() asm volatile("" ::: "memory")
#define BARR() __builtin_amdgcn_s_barrier()

#define RDA4(BUF, MB)                                                                    \
    _Pragma("unroll") for (int i2 = 0; i2 < 4; ++i2) {                                   \
        af[(MB) + i2][0] = *(const short8*)((BUF) + (arowb + ((MB) + i2) * 16) * 64 + ca0);\
        af[(MB) + i2][1] = *(const short8*)((BUF) + (arowb + ((MB) + i2) * 16) * 64 + ca1);\
    }
#define RDB4(BUF)                                                                        \
    _Pragma("unroll") for (int j2 = 0; j2 < 4; ++j2) {                                   \
        bf[j2][0] = *(const short8*)((BUF) + (brow + j2 * 16) * 64 + ca0);               \
        bf[j2][1] = *(const short8*)((BUF) + (brow + j2 * 16) * 64 + ca1);               \
    }
#define MMQ(MB, NB)                                                                      \
    __builtin_amdgcn_s_setprio(1);                                                       \
    _Pragma("unroll") for (int kk = 0; kk < 2; ++kk)                                     \
        _Pragma("unroll") for (int i2 = 0; i2 < 4; ++i2)                                 \
            _Pragma("unroll") for (int j2 = 0; j2 < 2; ++j2)                             \
                acc[(MB) + i2][(NB) + j2] =                                              \
                    MF(af[(MB) + i2][kk], bf[(NB) + j2][kk], acc[(MB) + i2][(NB) + j2]); \
    __builtin_amdgcn_s_setprio(0)

template <int SPLIT>
__global__ __launch_bounds__(512, 1) void gemm2sq(
    const unsigned short* __restrict__ A, int M, int Kfull, int nwg0,
    const unsigned short* __restrict__ BT_0, void* __restrict__ C_0, int N_0, int ldc_0,
    const float* __restrict__ bias_0, int epi_0,
    const unsigned short* __restrict__ BT_1, void* __restrict__ C_1, int N_1, int ldc_1,
    const float* __restrict__ bias_1, int epi_1) {
    __shared__ unsigned short aL[2][256 * 64];  // 64 KB
    __shared__ unsigned short bL[2][256 * 64];  // 64 KB

    int b = blockIdx.x;
    const unsigned short* BT;
    void* Cout;
    int N, ldc, epi;
    const float* bias;
    if (b < nwg0) {
        BT = BT_0; Cout = C_0; N = N_0; ldc = ldc_0; bias = bias_0; epi = epi_0;
    } else {
        b -= nwg0;
        BT = BT_1; Cout = C_1; N = N_1; ldc = ldc_1; bias = bias_1; epi = epi_1;
    }

    const int nby = M >> 8, nbx = N >> 8;
    const int nwg = nby * nbx;
    int sp = 0;
    if (SPLIT == 2) { sp = (b >= nwg) ? 1 : 0; b -= sp * nwg; }
    const int Keff = Kfull / SPLIT;
    const int koff = sp * Keff;

    const int slabw = nbx >> 3;
    const int xcd = b & 7;
    const int jj = b >> 3;
    const int bx = xcd * slabw + jj / nby;
    const int by = jj % nby;
    const int bm0 = by << 8, bn0 = bx << 8;

    const int tid = threadIdx.x, lane = tid & 63, wave = tid >> 6;
    const int wm = wave >> 2, wn = wave & 3;
    const int l15 = lane & 15, kl = lane >> 4;

    // staging: thread -> 16B granule; pre-swizzled source, linear LDS dest
    const int rh = tid >> 3;
    const int cb_s = (tid & 7) << 4;
    const int kx = (cb_s ^ ((rh & 7) << 4)) >> 1;

    const unsigned short* Abase = A + (size_t)(bm0 + rh) * Kfull + koff + kx;
    const unsigned short* Bbase = BT + (size_t)(bn0 + rh) * Kfull + koff + kx;

    auto stageA = [&](int v, int h) {
        const unsigned short* g = Abase + (size_t)v * 64 + (size_t)(h * 128) * Kfull;
        char* l = (char*)aL[v & 1] + h * 16384 + tid * 16;
        gload_lds16(g, l);
        gload_lds16(g + (size_t)64 * Kfull, l + 8192);
    };
    auto stageB = [&](int v, int h) {
        const unsigned short* g = Bbase + (size_t)v * 64 + (size_t)(h * 128) * Kfull;
        char* l = (char*)bL[v & 1] + h * 16384 + tid * 16;
        gload_lds16(g, l);
        gload_lds16(g + (size_t)64 * Kfull, l + 8192);
    };

    const int arowb = wm * 128 + l15;
    const int brow = wn * 64 + l15;
    const int sa = (l15 & 7) << 4;
    const int ca0 = ((kl * 16) ^ sa) >> 1;
    const int ca1 = ((64 + kl * 16) ^ sa) >> 1;

    f32x4 acc[8][4];
#pragma unroll
    for (int i = 0; i < 8; ++i)
#pragma unroll
        for (int j2 = 0; j2 < 4; ++j2) acc[i][j2] = (f32x4){0.f, 0.f, 0.f, 0.f};

    short8 af[8][2], bf[4][2];

    // prologue: tile0 (A,B) + B(1); wait tile0 (B(1)'s 4 loads stay in flight)
    stageA(0, 0); stageA(0, 1); stageB(0, 0); stageB(0, 1); stageB(1, 0); stageB(1, 1);
    asm volatile("s_waitcnt vmcnt(4)" ::: "memory");
    BARR();

    const int NI = (Keff >> 6) >> 1;
    for (int t2 = 0; t2 < NI; ++t2) {
        const int u = t2 << 1;
        const bool last = (t2 == NI - 1);
        const unsigned short* a0 = aL[0];
        const unsigned short* b0 = bL[0];
        const unsigned short* a1 = aL[1];
        const unsigned short* b1 = bL[1];

        // ph1: read tile u A0-3 + B full (16 b128); stage A(u+1) h0
        RDA4(a0, 0); RDB4(b0);
        stageA(u + 1, 0);
        FENCE(); BARR();
        MMQ(0, 0);
        BARR();
        // ph2: read A4-7 (8 b128); stage A(u+1) h1
        RDA4(a0, 4);
        stageA(u + 1, 1);
        FENCE(); BARR();
        MMQ(0, 2);
        BARR();
        // ph3: no reads; stage B(u+2) h0 (buf0-B last read ph1 - safe)
        if (!last) stageB(u + 2, 0);
        FENCE(); BARR();
        MMQ(4, 0);
        BARR();
        // ph4: no reads; stage B(u+2) h1; vmcnt gates tile u+1
        if (!last) stageB(u + 2, 1);
        FENCE(); BARR();
        MMQ(4, 2);
        if (last) { asm volatile("s_waitcnt vmcnt(0)" ::: "memory"); }
        else      { asm volatile("s_waitcnt vmcnt(4)" ::: "memory"); }
        BARR();

        // ph5: tile u+1: A0-3 + B full; stage A(u+2) h0 (buf0-A last read ph2 - safe)
        RDA4(a1, 0); RDB4(b1);
        if (!last) stageA(u + 2, 0);
        FENCE(); BARR();
        MMQ(0, 0);
        BARR();
        // ph6: A4-7; stage A(u+2) h1
        RDA4(a1, 4);
        if (!last) stageA(u + 2, 1);
        FENCE(); BARR();
        MMQ(0, 2);
        BARR();
        // ph7: no reads; stage B(u+3) h0 (buf1-B last read ph5 - safe)
        if (!last) stageB(u + 3, 0);
        FENCE(); BARR();
        MMQ(4, 0);
        BARR();
        // ph8: no reads; stage B(u+3) h1; vmcnt gates tile u+2
        if (!last) stageB(u + 3, 1);
        FENCE(); BARR();
        MMQ(4, 2);
        if (!last) { asm volatile("s_waitcnt vmcnt(4)" ::: "memory"); }
        BARR();
    }

    // epilogue (runtime epi: 0=bf16, 1=f32 split partial, 2=+bias gelu bf16)
    const int r0 = bm0 + wm * 128 + kl * 4;
    const int c0g = bn0 + wn * 64 + l15;
#pragma unroll
    for (int mi = 0; mi < 8; ++mi) {
#pragma unroll
        for (int nj = 0; nj < 4; ++nj) {
            int col = c0g + nj * 16;
#pragma unroll
            for (int r = 0; r < 4; ++r) {
                int row = r0 + mi * 16 + r;
                float v = acc[mi][nj][r];
                if (epi == 0) {
                    ((unsigned short*)Cout)[(size_t)row * ldc + col] = f2b(v);
                } else if (epi == 1) {
                    ((float*)Cout)[(size_t)sp * M * N + (size_t)row * ldc + col] = v;
                } else {
                    v += bias[col];
                    float z = 1.5957691216f * (v + 0.044715f * v * v * v);
                    float g = v / (1.0f + __expf(-z));  // 0.5v(1+tanh(z/... )) sigmoid form
                    ((unsigned short*)Cout)[(size_t)row * ldc + col] = f2b(g);
                }
            }
        }
    }
}

// ---------------- final reduce: out = fp0+fp1 + wp0+wp1 + b_ffn_o ----------------
__global__ __launch_bounds__(256) void final_reduce(const float* __restrict__ fp,
                                                    const float* __restrict__ wp,
                                                    const float* __restrict__ bias,
                                                    float* __restrict__ out) {
    size_t i = (size_t)blockIdx.x * 256 + threadIdx.x;
    const float4v* f0 = (const float4v*)fp;
    const float4v* f1 = (const float4v*)(fp + (size_t)SEQ * DM);
    const float4v* w0 = (const float4v*)wp;
    const float4v* w1 = (const float4v*)(wp + (size_t)SEQ * DM);
    const float4v* b4 = (const float4v*)bias;
    float4v v = f0[i] + f1[i] + w0[i] + w1[i] + b4[i & (DM / 4 - 1)];
    ((float4v*)out)[i] = v;
}

// ---------------- flash attention ----------------
__global__ __launch_bounds__(256, 2) void attn_kernel(const unsigned short* __restrict__ qkv,
                                                      const unsigned short* __restrict__ vT,
                                                      const float* __restrict__ bias,
                                                      unsigned short* __restrict__ attn_vec) {
    __shared__ unsigned short kL[64 * 264];
    __shared__ unsigned short vL[256 * 72];
    __shared__ unsigned short pL[4][16 * 72];

    int qb = blockIdx.x, head = blockIdx.y;
    int tid = threadIdx.x, lane = tid & 63, wave = tid >> 6;
    int q16 = lane & 15, q4 = lane >> 4;

    short8 qf[8];
    {
        const unsigned short* qp =
            qkv + (size_t)(qb * 64 + wave * 16 + q16) * (3 * DM) + head * DHEAD + (q4 << 3);
#pragma unroll
        for (int kk = 0; kk < 8; ++kk) qf[kk] = *(const short8*)(qp + kk * 32);
    }

    f32x4 o[16];
#pragma unroll
    for (int d = 0; d < 16; ++d) o[d] = (f32x4){0.f, 0.f, 0.f, 0.f};
    float m_run[4] = {-INFINITY, -INFINITY, -INFINITY, -INFINITY};
    float l_run[4] = {0.f, 0.f, 0.f, 0.f};
    int qrow0 = qb * 64 + wave * 16 + q4 * 4;

    for (int t = 0; t <= qb; ++t) {
        int kv0 = t * 64;
#pragma unroll
        for (int rr = 0; rr < 8; ++rr) {
            int i = tid + rr * 256;
            int row = i >> 5, c8 = (i & 31) << 3;
            *(ushort8v*)(kL + row * 264 + c8) =
                *(const ushort8v*)(qkv + (size_t)(kv0 + row) * (3 * DM) + DM + head * DHEAD + c8);
        }
#pragma unroll
        for (int rr = 0; rr < 8; ++rr) {
            int i = tid + rr * 256;
            int d = i >> 3, c8 = (i & 7) << 3;
            *(ushort8v*)(vL + d * 72 + c8) =
                *(const ushort8v*)(vT + (size_t)(head * DHEAD + d) * SEQ + kv0 + c8);
        }
        __syncthreads();

        f32x4 s[4];
#pragma unroll
        for (int c = 0; c < 4; ++c) s[c] = (f32x4){0.f, 0.f, 0.f, 0.f};
#pragma unroll
        for (int kk = 0; kk < 8; ++kk) {
#pragma unroll
            for (int c = 0; c < 4; ++c) {
                short8 kf = *(const short8*)(kL + (c * 16 + q16) * 264 + kk * 32 + (q4 << 3));
                s[c] = __builtin_amdgcn_mfma_f32_16x16x32_bf16(qf[kk], kf, s[c], 0, 0, 0);
            }
        }

        bool diag = (t == qb);
#pragma unroll
        for (int r = 0; r < 4; ++r) {
            int qr = qrow0 + r;
            float sv[4];
#pragma unroll
            for (int c = 0; c < 4; ++c) {
                float vv = s[c][r] * 0.0625f + bias[(size_t)qr * SEQ + kv0 + c * 16 + q16];
                if (diag && (kv0 + c * 16 + q16) > qr) vv = -1e30f;
                sv[c] = vv;
            }
            float m = fmaxf(fmaxf(sv[0], sv[1]), fmaxf(sv[2], sv[3]));
#pragma unroll
            for (int off = 1; off < 16; off <<= 1) m = fmaxf(m, __shfl_xor(m, off));
            float mn = fmaxf(m_run[r], m);
            float alpha = __expf(m_run[r] - mn);
            float psum = 0.f;
#pragma unroll
            for (int c = 0; c < 4; ++c) {
                float p = __expf(sv[c] - mn);
                psum += p;
                pL[wave][(q4 * 4 + r) * 72 + c * 16 + q16] = f2b(p);
            }
#pragma unroll
            for (int off = 1; off < 16; off <<= 1) psum += __shfl_xor(psum, off);
            l_run[r] = l_run[r] * alpha + psum;
            m_run[r] = mn;
#pragma unroll
            for (int d = 0; d < 16; ++d) o[d][r] *= alpha;
        }

#pragma unroll
        for (int ks = 0; ks < 2; ++ks) {
            short8 pa = *(const short8*)(pL[wave] + q16 * 72 + ks * 32 + (q4 << 3));
#pragma unroll
            for (int d = 0; d < 16; ++d) {
                short8 vb = *(const short8*)(vL + (d * 16 + q16) * 72 + ks * 32 + (q4 << 3));
                o[d] = __builtin_amdgcn_mfma_f32_16x16x32_bf16(pa, vb, o[d], 0, 0, 0);
            }
        }
        __syncthreads();
    }

#pragma unroll
    for (int r = 0; r < 4; ++r) {
        float inv = 1.0f / l_run[r];
#pragma unroll
        for (int d = 0; d < 16; ++d)
            attn_vec[(size_t)(qrow0 + r) * DM + head * DHEAD + d * 16 + q16] = f2b(o[d][r] * inv);
    }
}

// ---------------- launch ----------------
extern "C" void kernel_launch(void* const* d_in, const int* in_sizes, int n_in,
                              void* d_out, int out_size, void* d_ws, size_t ws_size,
                              hipStream_t stream) {
    const float* x = (const float*)d_in[0];
    const float* attn_bias = (const float*)d_in[1];
    const float* ln_scale = (const float*)d_in[2];
    const float* ln_offset = (const float*)d_in[3];
    const float* wq = (const float*)d_in[4];
    const float* wk = (const float*)d_in[5];
    const float* wv = (const float*)d_in[6];
    const float* wo = (const float*)d_in[7];
    const float* w_ffn = (const float*)d_in[8];
    const float* b_ffn = (const float*)d_in[9];
    const float* w_ffn_o = (const float*)d_in[10];
    const float* b_ffn_o = (const float*)d_in[11];
    float* out = (float*)d_out;

    char* p = (char*)d_ws;
    unsigned short* WT_qkv = (unsigned short*)p; p += (size_t)3 * DM * DM * 2;   // 96MB
    unsigned short* WT_o = (unsigned short*)p;   p += (size_t)DM * DM * 2;       // 32MB
    unsigned short* WT_f1 = (unsigned short*)p;  p += (size_t)DFF * DM * 2;      // 128MB
    unsigned short* WT_f2 = (unsigned short*)p;  p += (size_t)DM * DFF * 2;      // 128MB
    unsigned short* hB = (unsigned short*)p;     p += (size_t)SEQ * DM * 2;
    unsigned short* qkvB = (unsigned short*)p;   p += (size_t)SEQ * 3 * DM * 2;
    unsigned short* vTB = (unsigned short*)p;    p += (size_t)DM * SEQ * 2;
    unsigned short* avB = (unsigned short*)p;    p += (size_t)SEQ * DM * 2;
    unsigned short* ffB = (unsigned short*)p;    p += (size_t)SEQ * DFF * 2;

    // split-K partials alias dead weight buffers (fp by FFN2 after QKV done with WT_qkv;
    // wp by WO after FFN1 done with WT_f1)
    float* fp = (float*)WT_qkv;
    float* wp = (float*)WT_f1;

    transpose_cvt<float><<<dim3(DM / 64, DM / 64), 256, 0, stream>>>(wq, WT_qkv, DM, DM, DM, DM);
    transpose_cvt<float><<<dim3(DM / 64, DM / 64), 256, 0, stream>>>(wk, WT_qkv + (size_t)DM * DM, DM, DM, DM, DM);
    transpose_cvt<float><<<dim3(DM / 64, DM / 64), 256, 0, stream>>>(wv, WT_qkv + (size_t)2 * DM * DM, DM, DM, DM, DM);
    transpose_cvt<float><<<dim3(DM / 64, DM / 64), 256, 0, stream>>>(wo, WT_o, DM, DM, DM, DM);
    transpose_cvt<float><<<dim3(DFF / 64, DM / 64), 256, 0, stream>>>(w_ffn, WT_f1, DFF, DM, DM, DFF);
    transpose_cvt<float><<<dim3(DM / 64, DFF / 64), 256, 0, stream>>>(w_ffn_o, WT_f2, DM, DFF, DFF, DM);

    ln_kernel<<<SEQ, 256, 0, stream>>>(x, ln_scale, ln_offset, hB);

    // merged QKV (384 blocks, epi 0) + FFN1 (512 blocks, epi 2): 896 blocks
    gemm2sq<1><<<896, 512, 0, stream>>>(
        hB, SEQ, DM, 384,
        WT_qkv, qkvB, 3 * DM, 3 * DM, nullptr, 0,
        WT_f1, ffB, DFF, DFF, b_ffn, 2);

    transpose_cvt<unsigned short><<<dim3(DM / 64, SEQ / 64), 256, 0, stream>>>(qkvB + 2 * DM, vTB, 3 * DM, SEQ, SEQ, DM);

    attn_kernel<<<dim3(SEQ / 64, NHEADS), 256, 0, stream>>>(qkvB, vTB, attn_bias, avB);

    // WO split-K=2 -> wp partials (256 blocks)
    gemm2sq<2><<<256, 512, 0, stream>>>(
        avB, SEQ, DM, 256,
        WT_o, wp, DM, DM, nullptr, 1,
        nullptr, nullptr, DM, DM, nullptr, 1);
    // FFN2 split-K=2 -> fp partials (256 blocks)
    gemm2sq<2><<<256, 512, 0, stream>>>(
        ffB, SEQ, DFF, 256,
        WT_f2, fp, DM, DM, nullptr, 1,
        nullptr, nullptr, DM, DM, nullptr, 1);

    final_reduce<<<(SEQ * DM / 4) / 256, 256, 0, stream>>>(fp, wp, b_ffn_o, out);
}